// Round 5
// baseline (117.839 us; speedup 1.0000x reference)
//
#include <hip/hip_runtime.h>

#define SEQ 512
// alpha = log2(e)/sqrt(8); Q pre-scaled by sqrt(alpha) so score = exp2(q'.q')
#define SQRT_ALPHA     0.71419163f
#define INV_SQRT_ALPHA 1.40018452f
#define FLAG_MAGIC     0x5AD0BEEFu

__device__ __forceinline__ float2 pk_fma(float2 a, float2 b, float2 c) {
    return make_float2(fmaf(a.x, b.x, c.x), fmaf(a.y, b.y, c.y));
}

// Fused: analytic quantum feature + attention + output projection, ONE dispatch.
// grid (64 pairs, 4 chunks of 128 rows), block 512 = 8 waves.
// Phase 1 (qattn): exp[0]=prod_{1..7}cos(x_w+th_w); exp[k]=prod_{0..k}cos(...);
//   flash-style softmax (no max-sub: |score'|<=4.08) -> ctx rows for this
//   (pair,chunk), then device-scope release of flag[pair][chunk].
// Phase 2 (proj): block (b,h,chunk) handles tokens [chunk*128+h*16, +16):
//   spins (acquire) on the 8 same-(b,chunk) peer flags, then out = ctx.Wo^T+bo.
// Deadlock-free: 256 blocks <= 256 CUs, phase 1 runs unconditionally.
// Flags are in d_ws past ctx; poison 0xAAAAAAAA != FLAG_MAGIC so no zeroing.
__global__ __launch_bounds__(512) void fused_kernel(
    const float* __restrict__ x,      // fp32 [8,512,64]
    const float* __restrict__ theta,  // fp32 [8]
    const float* __restrict__ Wo,     // fp32 [64][64]
    const float* __restrict__ bo,     // fp32 [64]
    float* __restrict__ ctx,          // fp32 [4096][64] (ws)
    unsigned int* __restrict__ flags, // [64 pairs][4 chunks] (ws, poisoned)
    float* __restrict__ out)          // fp32 [4096][64]
{
    __shared__ float Qs[SEQ][8];      // 16 KB, pre-scaled by SQRT_ALPHA
    __shared__ float red[8][128][9];  // 36 KB, stride-9 conflict-free
    __shared__ float Ws[64][68];      // 17 KB, pitch 68: 16B-aligned, conflict-free

    const int pair  = blockIdx.x;     // b*8 + h
    const int chunk = blockIdx.y;     // 0..3 -> rows [128*chunk, +128)
    const int b = pair >> 3, h = pair & 7;
    const int tid = threadIdx.x;

    float th[8];
    #pragma unroll
    for (int w = 0; w < 8; w++) th[w] = theta[w];

    // ---- Phase 1a: build scaled Q, one row per thread ----
    {
        const int s = tid;
        const float* xp = x + ((size_t)(b * SEQ + s) * 64 + h * 8);
        float4 xa = *reinterpret_cast<const float4*>(xp);
        float4 xb = *reinterpret_cast<const float4*>(xp + 4);
        float c[8];
        c[0] = __cosf(xa.x + th[0]); c[1] = __cosf(xa.y + th[1]);
        c[2] = __cosf(xa.z + th[2]); c[3] = __cosf(xa.w + th[3]);
        c[4] = __cosf(xb.x + th[4]); c[5] = __cosf(xb.y + th[5]);
        c[6] = __cosf(xb.z + th[6]); c[7] = __cosf(xb.w + th[7]);
        float q[8];
        float pre = c[0];
        #pragma unroll
        for (int k = 1; k < 8; k++) { pre *= c[k]; q[k] = pre; }
        float suf = 1.f;
        #pragma unroll
        for (int w = 7; w >= 1; w--) suf *= c[w];
        q[0] = suf;
        float4 qa = make_float4(q[0]*SQRT_ALPHA, q[1]*SQRT_ALPHA, q[2]*SQRT_ALPHA, q[3]*SQRT_ALPHA);
        float4 qb = make_float4(q[4]*SQRT_ALPHA, q[5]*SQRT_ALPHA, q[6]*SQRT_ALPHA, q[7]*SQRT_ALPHA);
        *reinterpret_cast<float4*>(&Qs[s][0]) = qa;
        *reinterpret_cast<float4*>(&Qs[s][4]) = qb;
    }
    __syncthreads();

    const int lane = tid & 63;
    const int wv   = tid >> 6;        // 0..7 (j-slice: 64 j per wave)
    const int L    = lane & 31;       // rows L + {0,32,64,96} of the chunk

    float2 q01[4], q23[4], q45[4], q67[4];
    #pragma unroll
    for (int k = 0; k < 4; k++) {
        const float* qp = &Qs[chunk * 128 + 32 * k + L][0];
        q01[k] = *reinterpret_cast<const float2*>(qp + 0);
        q23[k] = *reinterpret_cast<const float2*>(qp + 2);
        q45[k] = *reinterpret_cast<const float2*>(qp + 4);
        q67[k] = *reinterpret_cast<const float2*>(qp + 6);
    }

    float2 a01[4], a23[4], a45[4], a67[4];
    float l[4];
    #pragma unroll
    for (int k = 0; k < 4; k++) {
        a01[k] = make_float2(0.f, 0.f); a23[k] = a01[k];
        a45[k] = a01[k]; a67[k] = a01[k]; l[k] = 0.f;
    }

    // half-waves take different j: 2 distinct LDS addrs/instr = free 2-way
    const float* up = &Qs[wv * 64 + 32 * (lane >> 5)][0];
    #pragma unroll 8
    for (int i = 0; i < 32; i++) {
        float2 u0 = *reinterpret_cast<const float2*>(up + i * 8 + 0);
        float2 u1 = *reinterpret_cast<const float2*>(up + i * 8 + 2);
        float2 u2 = *reinterpret_cast<const float2*>(up + i * 8 + 4);
        float2 u3 = *reinterpret_cast<const float2*>(up + i * 8 + 6);
        #pragma unroll
        for (int k = 0; k < 4; k++) {
            float2 d = pk_fma(q01[k], u0, pk_fma(q23[k], u1, pk_fma(q45[k], u2,
                       make_float2(q67[k].x * u3.x, q67[k].y * u3.y))));
            float e = __builtin_amdgcn_exp2f(d.x + d.y);
            l[k] += e;
            float2 ev = make_float2(e, e);
            a01[k] = pk_fma(ev, u0, a01[k]); a23[k] = pk_fma(ev, u1, a23[k]);
            a45[k] = pk_fma(ev, u2, a45[k]); a67[k] = pk_fma(ev, u3, a67[k]);
        }
    }

    // merge the two j-halves (lane ^ 32)
    #pragma unroll
    for (int k = 0; k < 4; k++) {
        a01[k].x += __shfl_xor(a01[k].x, 32); a01[k].y += __shfl_xor(a01[k].y, 32);
        a23[k].x += __shfl_xor(a23[k].x, 32); a23[k].y += __shfl_xor(a23[k].y, 32);
        a45[k].x += __shfl_xor(a45[k].x, 32); a45[k].y += __shfl_xor(a45[k].y, 32);
        a67[k].x += __shfl_xor(a67[k].x, 32); a67[k].y += __shfl_xor(a67[k].y, 32);
        l[k]     += __shfl_xor(l[k], 32);
    }

    if (lane < 32) {
        #pragma unroll
        for (int k = 0; k < 4; k++) {
            float* rp = &red[wv][32 * k + L][0];
            rp[0] = a01[k].x; rp[1] = a01[k].y; rp[2] = a23[k].x; rp[3] = a23[k].y;
            rp[4] = a45[k].x; rp[5] = a45[k].y; rp[6] = a67[k].x; rp[7] = a67[k].y;
            rp[8] = l[k];
        }
    }
    __syncthreads();

    // ---- Phase 1b: cross-wave reduce, write ctx (1024 items / 512 threads) ----
    #pragma unroll
    for (int ii = 0; ii < 2; ii++) {
        int idx = ii * 512 + tid;
        int lr = idx >> 3, d = idx & 7;
        float v = 0.f, ll = 0.f;
        #pragma unroll
        for (int w = 0; w < 8; w++) { v += red[w][lr][d]; ll += red[w][lr][8]; }
        int row = chunk * 128 + lr;
        ctx[(size_t)(b * SEQ + row) * 64 + h * 8 + d] = v * INV_SQRT_ALPHA / ll;
    }
    __syncthreads();   // per-wave vmcnt(0) drain: all ctx stores in L2

    // ---- publish: device-scope release of this block's flag ----
    if (tid == 0) {
        __threadfence();   // agent fence: L2 writeback so other XCDs see ctx
        __hip_atomic_store(&flags[pair * 4 + chunk], FLAG_MAGIC,
                           __ATOMIC_RELEASE, __HIP_MEMORY_SCOPE_AGENT);
    }

    // ---- Phase 2 prep: stage Wo while (possibly) waiting ----
    #pragma unroll
    for (int i = 0; i < 8; i++) {
        int idx = i * 512 + tid;
        Ws[idx >> 6][idx & 63] = Wo[idx];
    }

    // spin on the 8 same-(b,chunk) peer flags
    if (tid < 8) {
        const unsigned int* fp = &flags[(b * 8 + tid) * 4 + chunk];
        while (__hip_atomic_load(fp, __ATOMIC_ACQUIRE, __HIP_MEMORY_SCOPE_AGENT)
               != FLAG_MAGIC) {
            __builtin_amdgcn_s_sleep(1);
        }
    }
    __syncthreads();
    __threadfence();   // acquire side: invalidate local L2 before ctx reads

    // ---- Phase 2: proj for tokens [chunk*128 + h*16, +16) ----
    // wave wv handles 2 tokens; lane = e
    const int e  = lane;
    const int t0 = chunk * 128 + h * 16 + wv * 2;
    const float4* c0 = reinterpret_cast<const float4*>(ctx + (size_t)(b * SEQ + t0) * 64);
    const float4* c1 = reinterpret_cast<const float4*>(ctx + (size_t)(b * SEQ + t0 + 1) * 64);
    float a0 = 0.f, a1 = 0.f;
    #pragma unroll 4
    for (int k4 = 0; k4 < 16; k4++) {
        float4 w  = *reinterpret_cast<const float4*>(&Ws[e][k4 * 4]);
        float4 x0 = c0[k4];            // wave-uniform broadcast
        float4 x1 = c1[k4];
        a0 += x0.x*w.x + x0.y*w.y + x0.z*w.z + x0.w*w.w;
        a1 += x1.x*w.x + x1.y*w.y + x1.z*w.z + x1.w*w.w;
    }
    float bb = bo[e];
    out[(size_t)(b * SEQ + t0) * 64 + e]     = a0 + bb;
    out[(size_t)(b * SEQ + t0 + 1) * 64 + e] = a1 + bb;
}

extern "C" void kernel_launch(void* const* d_in, const int* in_sizes, int n_in,
                              void* d_out, int out_size, void* d_ws, size_t ws_size,
                              hipStream_t stream) {
    const float* x     = (const float*)d_in[0];  // [8,512,64]
    const float* theta = (const float*)d_in[1];  // [8]
    const float* Wo    = (const float*)d_in[2];  // [64,64]
    const float* bo    = (const float*)d_in[3];  // [64]
    float* out = (float*)d_out;                  // [8,512,64]
    float* ctx = (float*)d_ws;                   // 1 MB fp32 scratch
    unsigned int* flags = (unsigned int*)((char*)d_ws + (1u << 20)); // 256 flags

    fused_kernel<<<dim3(64, 4), 512, 0, stream>>>(x, theta, Wo, bo, ctx, flags, out);
}

// Round 6
// 88.650 us; speedup vs baseline: 1.3293x; 1.3293x over previous
//
#include <hip/hip_runtime.h>

// alpha = log2(e)/sqrt(8); Q pre-scaled by sqrt(alpha) so score = exp2(q'.q')
#define SQRT_ALPHA     0.71419163f
#define INV_SQRT_ALPHA 1.40018452f

__device__ __forceinline__ float2 pk_fma(float2 a, float2 b, float2 c) {
    return make_float2(fmaf(a.x, b.x, c.x), fmaf(a.y, b.y, c.y));
}

// Single dispatch, fully block-independent (no cross-block sync/atomics).
// grid (8 batches, 32 chunks of 16 tokens), block 512 = 8 waves.
// Per head h: build Q_h for all 512 tokens (8 cos/row, double-buffered LDS),
// flash attention for this block's 16 rows (no max-sub: |score'|<=4.08),
// stash ctx columns h*8..h*8+7 in LDS. Then project 16 tokens -> out.
// blockIdx.x = b so all 32 blocks of a batch share one XCD's L2 x-slab.
__global__ __launch_bounds__(512) void fused_kernel(
    const float* __restrict__ x,      // fp32 [8,512,64]
    const float* __restrict__ theta,  // fp32 [8]
    const float* __restrict__ Wo,     // fp32 [64][64]
    const float* __restrict__ bo,     // fp32 [64]
    float* __restrict__ out)          // fp32 [4096][64]
{
    __shared__ float Qs[2][512 * 10]; // 40 KB; pitch 10 (40 B): b64-aligned,
                                      // 16 distinct rows -> 16 distinct banks
    __shared__ float Ws[64][68];      // 17 KB; pitch 68: 16B-aligned rows
    __shared__ float red[8][4][16][10]; // 20 KB partials [wave][jclass][row][9 used]
    __shared__ float ctxL[16][68];    // 4.3 KB ctx rows (64 cols + pad)

    const int b     = blockIdx.x;     // 0..7
    const int chunk = blockIdx.y;     // 0..31 -> tokens [16*chunk, +16)
    const int tid  = threadIdx.x;
    const int lane = tid & 63;
    const int wv   = tid >> 6;        // 0..7: j-slice [64*wv, +64)

    // stage Wo once
    #pragma unroll
    for (int i = 0; i < 8; i++) {
        int idx = i * 512 + tid;
        Ws[idx >> 6][idx & 63] = Wo[idx];
    }
    float th[8];
    #pragma unroll
    for (int w = 0; w < 8; w++) th[w] = theta[w];

    const int g    = lane & 3;        // row group: local rows 4g..4g+3
    const int jsub = lane >> 2;       // 0..15: j = wv*64 + jsub + 16*i
    const int sub  = jsub >> 2;       // 0..3: residual j-class after butterfly

    for (int h = 0; h < 8; h++) {
        float* Q = Qs[h & 1];
        // ---- build scaled Q_h: one token per thread ----
        // exp[0] = prod_{1..7} cos(x_w+th_w); exp[k] = prod_{0..k} cos(...)
        {
            const float* xp = x + ((size_t)(b * 512 + tid) * 64 + h * 8);
            float4 xa = *reinterpret_cast<const float4*>(xp);
            float4 xb = *reinterpret_cast<const float4*>(xp + 4);
            float c[8];
            c[0] = __cosf(xa.x + th[0]); c[1] = __cosf(xa.y + th[1]);
            c[2] = __cosf(xa.z + th[2]); c[3] = __cosf(xa.w + th[3]);
            c[4] = __cosf(xb.x + th[4]); c[5] = __cosf(xb.y + th[5]);
            c[6] = __cosf(xb.z + th[6]); c[7] = __cosf(xb.w + th[7]);
            float q[8];
            float pre = c[0];
            #pragma unroll
            for (int k = 1; k < 8; k++) { pre *= c[k]; q[k] = pre; }
            float suf = 1.f;
            #pragma unroll
            for (int w = 7; w >= 1; w--) suf *= c[w];
            q[0] = suf;
            float* qd = Q + tid * 10;
            *reinterpret_cast<float2*>(qd + 0) = make_float2(q[0]*SQRT_ALPHA, q[1]*SQRT_ALPHA);
            *reinterpret_cast<float2*>(qd + 2) = make_float2(q[2]*SQRT_ALPHA, q[3]*SQRT_ALPHA);
            *reinterpret_cast<float2*>(qd + 4) = make_float2(q[4]*SQRT_ALPHA, q[5]*SQRT_ALPHA);
            *reinterpret_cast<float2*>(qd + 6) = make_float2(q[6]*SQRT_ALPHA, q[7]*SQRT_ALPHA);
        }
        __syncthreads();   // sync A: Q_h complete

        // ---- j-loop: 4 rows/lane x 4 j/lane ----
        float2 q01[4], q23[4], q45[4], q67[4];
        #pragma unroll
        for (int k = 0; k < 4; k++) {
            const float* qp = Q + (chunk * 16 + 4 * g + k) * 10;
            q01[k] = *reinterpret_cast<const float2*>(qp + 0);
            q23[k] = *reinterpret_cast<const float2*>(qp + 2);
            q45[k] = *reinterpret_cast<const float2*>(qp + 4);
            q67[k] = *reinterpret_cast<const float2*>(qp + 6);
        }
        float2 a01[4], a23[4], a45[4], a67[4];
        float l[4];
        #pragma unroll
        for (int k = 0; k < 4; k++) {
            a01[k] = make_float2(0.f, 0.f); a23[k] = a01[k];
            a45[k] = a01[k]; a67[k] = a01[k]; l[k] = 0.f;
        }
        #pragma unroll
        for (int i = 0; i < 4; i++) {
            const float* up = Q + (wv * 64 + jsub + 16 * i) * 10;
            float2 u0 = *reinterpret_cast<const float2*>(up + 0);
            float2 u1 = *reinterpret_cast<const float2*>(up + 2);
            float2 u2 = *reinterpret_cast<const float2*>(up + 4);
            float2 u3 = *reinterpret_cast<const float2*>(up + 6);
            #pragma unroll
            for (int k = 0; k < 4; k++) {
                float2 d = pk_fma(q01[k], u0, pk_fma(q23[k], u1, pk_fma(q45[k], u2,
                           make_float2(q67[k].x * u3.x, q67[k].y * u3.y))));
                float e = __builtin_amdgcn_exp2f(d.x + d.y);
                l[k] += e;
                float2 ev = make_float2(e, e);
                a01[k] = pk_fma(ev, u0, a01[k]); a23[k] = pk_fma(ev, u1, a23[k]);
                a45[k] = pk_fma(ev, u2, a45[k]); a67[k] = pk_fma(ev, u3, a67[k]);
            }
        }
        // butterfly over jsub bits 0,1 (lane bits 2,3): 16 j-slices -> 4
        #pragma unroll
        for (int k = 0; k < 4; k++) {
            #pragma unroll
            for (int m = 4; m <= 8; m <<= 1) {
                a01[k].x += __shfl_xor(a01[k].x, m); a01[k].y += __shfl_xor(a01[k].y, m);
                a23[k].x += __shfl_xor(a23[k].x, m); a23[k].y += __shfl_xor(a23[k].y, m);
                a45[k].x += __shfl_xor(a45[k].x, m); a45[k].y += __shfl_xor(a45[k].y, m);
                a67[k].x += __shfl_xor(a67[k].x, m); a67[k].y += __shfl_xor(a67[k].y, m);
                l[k]     += __shfl_xor(l[k], m);
            }
        }
        if ((jsub & 3) == 0) {        // one writer per (wv,sub,g)
            #pragma unroll
            for (int k = 0; k < 4; k++) {
                float* rp = &red[wv][sub][4 * g + k][0];
                *reinterpret_cast<float2*>(rp + 0) = a01[k];
                *reinterpret_cast<float2*>(rp + 2) = a23[k];
                *reinterpret_cast<float2*>(rp + 4) = a45[k];
                *reinterpret_cast<float2*>(rp + 6) = a67[k];
                rp[8] = l[k];
            }
        }
        __syncthreads();   // sync B: partials complete

        // final reduce (waves 0-1) overlaps next head's Q-build on waves 2-7.
        // Safe: red(h+1) writes are gated by sync A(h+1)+loop, and every
        // thread's build(h+1) follows its own step here (program order).
        if (tid < 128) {
            int row = tid >> 3, d = tid & 7;
            float sv = 0.f, sl = 0.f;
            #pragma unroll
            for (int w2 = 0; w2 < 8; w2++) {
                #pragma unroll
                for (int s2 = 0; s2 < 4; s2++) {
                    sv += red[w2][s2][row][d];
                    sl += red[w2][s2][row][8];   // broadcast across d-lanes
                }
            }
            ctxL[row][h * 8 + d] = sv * INV_SQRT_ALPHA / sl;
        }
    }
    __syncthreads();

    // ---- proj: 16 tokens x 64 e over 512 threads (2 outputs each) ----
    #pragma unroll
    for (int ii = 0; ii < 2; ii++) {
        int idx = ii * 512 + tid;
        int r = idx >> 6, e = idx & 63;
        float acc = bo[e];
        #pragma unroll 4
        for (int k4 = 0; k4 < 16; k4++) {
            float4 w = *reinterpret_cast<const float4*>(&Ws[e][k4 * 4]);
            float4 c = *reinterpret_cast<const float4*>(&ctxL[r][k4 * 4]); // broadcast
            acc += c.x*w.x + c.y*w.y + c.z*w.z + c.w*w.w;
        }
        out[(size_t)(b * 512 + chunk * 16 + r) * 64 + e] = acc;
    }
}

extern "C" void kernel_launch(void* const* d_in, const int* in_sizes, int n_in,
                              void* d_out, int out_size, void* d_ws, size_t ws_size,
                              hipStream_t stream) {
    const float* x     = (const float*)d_in[0];  // [8,512,64]
    const float* theta = (const float*)d_in[1];  // [8]
    const float* Wo    = (const float*)d_in[2];  // [64,64]
    const float* bo    = (const float*)d_in[3];  // [64]
    float* out = (float*)d_out;                  // [8,512,64]

    fused_kernel<<<dim3(8, 32), 512, 0, stream>>>(x, theta, Wo, bo, out);
}

// Round 7
// 76.317 us; speedup vs baseline: 1.5441x; 1.1616x over previous
//
#include <hip/hip_runtime.h>

#define SEQ 512
// alpha = log2(e)/sqrt(8); Q pre-scaled by sqrt(alpha) so score = exp2(q'.q')
#define SQRT_ALPHA     0.71419163f
#define INV_SQRT_ALPHA 1.40018452f

__device__ __forceinline__ float2 pk_fma(float2 a, float2 b, float2 c) {
    return make_float2(fmaf(a.x, b.x, c.x), fmaf(a.y, b.y, c.y));
}

// One compute dispatch (plus a 1MB memset node). Block = (pair=(b,h), chunk
// of 128 rows), identical to the proven R4 qattn partition. After computing
// its ctx slab [128 rows x 8 d] in LDS, each block scatters its partial
// projection out[row,e] += ctx.Wo^T via HW fp32 atomics (commutative ->
// no cross-block ordering, no fences, no flags). h==0 block adds b_o.
__global__ __launch_bounds__(512) void qattn_proj_kernel(
    const float* __restrict__ x,      // fp32 [8,512,64]
    const float* __restrict__ theta,  // fp32 [8]
    const float* __restrict__ Wo,     // fp32 [64][64]
    const float* __restrict__ bo,     // fp32 [64]
    float* __restrict__ out)          // fp32 [4096][64], pre-zeroed
{
    __shared__ float Qs[SEQ][8];      // 16 KB, pre-scaled by SQRT_ALPHA
    __shared__ float red[8][128][9];  // 36 KB, stride-9 conflict-free
    __shared__ float ctxL[128][8];    // 4 KB: this block's ctx slab

    const int pair  = blockIdx.x;     // b*8 + h
    const int chunk = blockIdx.y;     // 0..3 -> rows [128*chunk, +128)
    const int b = pair >> 3, h = pair & 7;
    const int tid = threadIdx.x;

    float th[8];
    #pragma unroll
    for (int w = 0; w < 8; w++) th[w] = theta[w];

    // ---- Phase 1a: build scaled Q, one row per thread (R4-identical) ----
    {
        const int s = tid;
        const float* xp = x + ((size_t)(b * SEQ + s) * 64 + h * 8);
        float4 xa = *reinterpret_cast<const float4*>(xp);
        float4 xb = *reinterpret_cast<const float4*>(xp + 4);
        float c[8];
        c[0] = __cosf(xa.x + th[0]); c[1] = __cosf(xa.y + th[1]);
        c[2] = __cosf(xa.z + th[2]); c[3] = __cosf(xa.w + th[3]);
        c[4] = __cosf(xb.x + th[4]); c[5] = __cosf(xb.y + th[5]);
        c[6] = __cosf(xb.z + th[6]); c[7] = __cosf(xb.w + th[7]);
        float q[8];
        float pre = c[0];
        #pragma unroll
        for (int k = 1; k < 8; k++) { pre *= c[k]; q[k] = pre; }
        float suf = 1.f;
        #pragma unroll
        for (int w = 7; w >= 1; w--) suf *= c[w];
        q[0] = suf;
        float4 qa = make_float4(q[0]*SQRT_ALPHA, q[1]*SQRT_ALPHA, q[2]*SQRT_ALPHA, q[3]*SQRT_ALPHA);
        float4 qb = make_float4(q[4]*SQRT_ALPHA, q[5]*SQRT_ALPHA, q[6]*SQRT_ALPHA, q[7]*SQRT_ALPHA);
        *reinterpret_cast<float4*>(&Qs[s][0]) = qa;
        *reinterpret_cast<float4*>(&Qs[s][4]) = qb;
    }
    __syncthreads();

    const int lane = tid & 63;
    const int wv   = tid >> 6;        // 0..7 (j-slice: 64 j per wave)
    const int L    = lane & 31;       // rows L + {0,32,64,96} of the chunk

    float2 q01[4], q23[4], q45[4], q67[4];
    #pragma unroll
    for (int k = 0; k < 4; k++) {
        const float* qp = &Qs[chunk * 128 + 32 * k + L][0];
        q01[k] = *reinterpret_cast<const float2*>(qp + 0);
        q23[k] = *reinterpret_cast<const float2*>(qp + 2);
        q45[k] = *reinterpret_cast<const float2*>(qp + 4);
        q67[k] = *reinterpret_cast<const float2*>(qp + 6);
    }

    float2 a01[4], a23[4], a45[4], a67[4];
    float l[4];
    #pragma unroll
    for (int k = 0; k < 4; k++) {
        a01[k] = make_float2(0.f, 0.f); a23[k] = a01[k];
        a45[k] = a01[k]; a67[k] = a01[k]; l[k] = 0.f;
    }

    // half-waves take different j: 2 distinct LDS addrs/instr = free 2-way
    const float* up = &Qs[wv * 64 + 32 * (lane >> 5)][0];
    #pragma unroll 8
    for (int i = 0; i < 32; i++) {
        float2 u0 = *reinterpret_cast<const float2*>(up + i * 8 + 0);
        float2 u1 = *reinterpret_cast<const float2*>(up + i * 8 + 2);
        float2 u2 = *reinterpret_cast<const float2*>(up + i * 8 + 4);
        float2 u3 = *reinterpret_cast<const float2*>(up + i * 8 + 6);
        #pragma unroll
        for (int k = 0; k < 4; k++) {
            float2 d = pk_fma(q01[k], u0, pk_fma(q23[k], u1, pk_fma(q45[k], u2,
                       make_float2(q67[k].x * u3.x, q67[k].y * u3.y))));
            float e = __builtin_amdgcn_exp2f(d.x + d.y);
            l[k] += e;
            float2 ev = make_float2(e, e);
            a01[k] = pk_fma(ev, u0, a01[k]); a23[k] = pk_fma(ev, u1, a23[k]);
            a45[k] = pk_fma(ev, u2, a45[k]); a67[k] = pk_fma(ev, u3, a67[k]);
        }
    }

    // merge the two j-halves (lane ^ 32)
    #pragma unroll
    for (int k = 0; k < 4; k++) {
        a01[k].x += __shfl_xor(a01[k].x, 32); a01[k].y += __shfl_xor(a01[k].y, 32);
        a23[k].x += __shfl_xor(a23[k].x, 32); a23[k].y += __shfl_xor(a23[k].y, 32);
        a45[k].x += __shfl_xor(a45[k].x, 32); a45[k].y += __shfl_xor(a45[k].y, 32);
        a67[k].x += __shfl_xor(a67[k].x, 32); a67[k].y += __shfl_xor(a67[k].y, 32);
        l[k]     += __shfl_xor(l[k], 32);
    }

    if (lane < 32) {
        #pragma unroll
        for (int k = 0; k < 4; k++) {
            float* rp = &red[wv][32 * k + L][0];
            rp[0] = a01[k].x; rp[1] = a01[k].y; rp[2] = a23[k].x; rp[3] = a23[k].y;
            rp[4] = a45[k].x; rp[5] = a45[k].y; rp[6] = a67[k].x; rp[7] = a67[k].y;
            rp[8] = l[k];
        }
    }
    __syncthreads();

    // ---- Phase 1b: cross-wave reduce -> ctx slab in LDS ----
    #pragma unroll
    for (int ii = 0; ii < 2; ii++) {
        int idx = ii * 512 + tid;
        int lr = idx >> 3, d = idx & 7;
        float v = 0.f, ll = 0.f;
        #pragma unroll
        for (int w = 0; w < 8; w++) { v += red[w][lr][d]; ll += red[w][lr][8]; }
        ctxL[lr][d] = v * INV_SQRT_ALPHA / ll;
    }
    __syncthreads();

    // ---- Phase 2: partial projection, scattered via fp32 HW atomics ----
    // thread (e = lane-ish): e = tid & 63, row group rg = tid >> 6 (16 rows).
    // contribution(row,e) = sum_d ctxL[row][d] * Wo[e][h*8+d]  (+ bo[e] @ h==0)
    {
        const int e  = tid & 63;
        const int rg = tid >> 6;
        const float4* wp = reinterpret_cast<const float4*>(Wo + e * 64 + h * 8);
        float4 w0 = wp[0], w1 = wp[1];
        const float bb = (h == 0) ? bo[e] : 0.f;
        float* ob = out + ((size_t)(b * SEQ + chunk * 128 + rg * 16)) * 64 + e;
        #pragma unroll 4
        for (int r = 0; r < 16; r++) {
            // wave-uniform LDS broadcast (all lanes in a wave share rg)
            float4 c0 = *reinterpret_cast<const float4*>(&ctxL[rg * 16 + r][0]);
            float4 c1 = *reinterpret_cast<const float4*>(&ctxL[rg * 16 + r][4]);
            float s = bb + c0.x*w0.x + c0.y*w0.y + c0.z*w0.z + c0.w*w0.w
                         + c1.x*w1.x + c1.y*w1.y + c1.z*w1.z + c1.w*w1.w;
            unsafeAtomicAdd(ob + (size_t)r * 64, s);  // global_atomic_add_f32
        }
    }
}

extern "C" void kernel_launch(void* const* d_in, const int* in_sizes, int n_in,
                              void* d_out, int out_size, void* d_ws, size_t ws_size,
                              hipStream_t stream) {
    const float* x     = (const float*)d_in[0];  // [8,512,64]
    const float* theta = (const float*)d_in[1];  // [8]
    const float* Wo    = (const float*)d_in[2];  // [64,64]
    const float* bo    = (const float*)d_in[3];  // [64]
    float* out = (float*)d_out;                  // [8,512,64]

    // zero the accumulation target (graph-capturable async memset node)
    hipMemsetAsync(out, 0, (size_t)out_size * sizeof(float), stream);
    qattn_proj_kernel<<<dim3(64, 4), 512, 0, stream>>>(x, theta, Wo, bo, out);
}